// Round 11
// baseline (177.090 us; speedup 1.0000x reference)
//
#include <hip/hip_runtime.h>

#define NH 4
#define DH 64
#define SS 1024
#define CC 256

typedef __attribute__((ext_vector_type(8))) short short8;
typedef __attribute__((ext_vector_type(4))) float floatx4;
typedef __attribute__((ext_vector_type(16))) float floatx16;
typedef __attribute__((ext_vector_type(2))) unsigned uint2v;

#define MFMA16(a, b, c) __builtin_amdgcn_mfma_f32_16x16x32_bf16(a, b, c, 0, 0, 0)
#define MFMA32(a, b, c) __builtin_amdgcn_mfma_f32_32x32x16_bf16(a, b, c, 0, 0, 0)

// q scale 0.125 folded with log2(e) so attention can use exp2 directly
#define QSCALE 0.18033688011112042f

__device__ __forceinline__ short f2bf(float f) {
    union { float f; unsigned u; } v; v.f = f;
    unsigned r = (v.u + 0x7fffu + ((v.u >> 16) & 1u)) >> 16;
    return (short)r;
}
__device__ __forceinline__ unsigned bfrn(float f) {
    union { float f; unsigned u; } v; v.f = f;
    return (v.u + 0x7fffu + ((v.u >> 16) & 1u)) >> 16;
}
__device__ __forceinline__ unsigned pk2_trunc(float a, float b) {
    union { float f; unsigned u; } ua, ub; ua.f = a; ub.f = b;
    return (ua.u >> 16) | (ub.u & 0xFFFF0000u);
}
__device__ __forceinline__ unsigned pk2_rn(float a, float b) {
    return bfrn(a) | (bfrn(b) << 16);
}

// ------- merged prep: x [B][C][S] f32 -> xs [B][S][C] bf16 ; weight transposes -------
__global__ __launch_bounds__(256) void k_prep(const float* __restrict__ x,
                                              const float* __restrict__ Wqkv,
                                              const float* __restrict__ Wout,
                                              short* __restrict__ xs,
                                              short* __restrict__ Wqkv_t,
                                              short* __restrict__ Wout_t) {
    int bid = blockIdx.x;
    if (bid < 2048) {
        __shared__ float tile[64][65];
        int b = bid >> 6;
        int s0 = ((bid >> 2) & 15) * 64;
        int c0 = (bid & 3) * 64;
        int t = threadIdx.x;
        int tx = t & 63, ty = t >> 6;
        for (int i = 0; i < 16; ++i) {
            int c = ty + i * 4;
            tile[tx][c] = x[((b * CC) + (c0 + c)) * SS + s0 + tx];
        }
        __syncthreads();
        for (int i = 0; i < 8; ++i) {
            int s = (t >> 5) + i * 8;
            int cp = (t & 31) * 2;
            short2 v;
            v.x = f2bf(tile[s][cp]);
            v.y = f2bf(tile[s][cp + 1]);
            *(short2*)(&xs[((b * SS) + (s0 + s)) * CC + c0 + cp]) = v;
        }
    } else {
        int idx = (bid - 2048) * 256 + threadIdx.x;
        if (idx < 768 * 256) {
            int n = idx >> 8, k = idx & 255;
            Wqkv_t[idx] = f2bf(Wqkv[k * 768 + n]);
        } else {
            int j = idx - 768 * 256;
            int c = j >> 8, k = j & 255;
            Wout_t[j] = f2bf(Wout[k * 256 + c]);
        }
    }
}

// ---------------- QKV GEMM: [32768,256] @ [256,768] ---------------- (R9 version)
__global__ __launch_bounds__(256) void k_qkv(const short* __restrict__ xs,
                                             const short* __restrict__ Wt,
                                             const float* __restrict__ bqkv,
                                             short* __restrict__ qtw,
                                             short* __restrict__ kw,
                                             short* __restrict__ vtw) {
    __shared__ short smem[10240];  // As | Bs in loop; transpose tile after
    short* As = smem;
    short* Bs = smem + 5120;
    int bid = blockIdx.x;
    int idx = bid >> 3;
    int m0 = ((bid & 7) * 32 + idx / 6) * 128;
    int n0 = (idx % 6) * 128;
    int t = threadIdx.x;
    int lane = t & 63, wid = t >> 6;
    int wr = wid >> 1, wc = wid & 1;
    int c16 = lane & 15, qd = lane >> 4;

    floatx4 acc[4][4] = {};
    short8 pa[2], pb[2];

    for (int j = 0; j < 2; ++j) {
        int id = j * 256 + t, row = id >> 2, cc = id & 3;
        pa[j] = *(const short8*)(&xs[(m0 + row) * CC + cc * 8]);
        pb[j] = *(const short8*)(&Wt[(n0 + row) * CC + cc * 8]);
    }
    for (int kt = 0; kt < 8; ++kt) {
        if (kt) __syncthreads();
        for (int j = 0; j < 2; ++j) {
            int id = j * 256 + t, row = id >> 2, cc = id & 3;
            *(short8*)(&As[row * 40 + cc * 8]) = pa[j];
            *(short8*)(&Bs[row * 40 + cc * 8]) = pb[j];
        }
        __syncthreads();
        if (kt < 7) {
            for (int j = 0; j < 2; ++j) {
                int id = j * 256 + t, row = id >> 2, cc = id & 3;
                pa[j] = *(const short8*)(&xs[(m0 + row) * CC + (kt + 1) * 32 + cc * 8]);
                pb[j] = *(const short8*)(&Wt[(n0 + row) * CC + (kt + 1) * 32 + cc * 8]);
            }
        }
        short8 av[4], bv[4];
        for (int i = 0; i < 4; ++i) {
            av[i] = *(const short8*)(&As[(wr * 64 + i * 16 + c16) * 40 + qd * 8]);
            bv[i] = *(const short8*)(&Bs[(wc * 64 + i * 16 + c16) * 40 + qd * 8]);
        }
        for (int mi = 0; mi < 4; ++mi)
            for (int ni = 0; ni < 4; ++ni)
                acc[mi][ni] = MFMA16(av[mi], bv[ni], acc[mi][ni]);
    }

    int b = m0 >> 10, sbase = m0 & 1023;
    int seg = (n0 >> 6) + wc;  // this wave's segment: h*3 + (0=q,1=k,2=v)
    float bias4[4];
    for (int ni = 0; ni < 4; ++ni)
        bias4[ni] = bqkv[n0 + wc * 64 + ni * 16 + c16];

    // ---- Q/V passes: LDS transpose [s][d]->[d][s], then coalesced stores.
    int seg0 = n0 >> 6;
    short* Tt = smem;
    for (int s2 = 0; s2 < 2; ++s2) {
        int sg = seg0 + s2;
        int type = sg % 3;
        if (type == 1) continue;  // k handled below
        float sc = (type == 0) ? QSCALE : 1.f;
        __syncthreads();
        if (wc == s2) {
            for (int mi = 0; mi < 4; ++mi)
                for (int ni = 0; ni < 4; ++ni)
                    for (int r = 0; r < 4; ++r)
                        Tt[(ni * 16 + c16) * 136 + wr * 64 + mi * 16 + qd * 4 + r] =
                            f2bf((acc[mi][ni][r] + bias4[ni]) * sc);
        }
        __syncthreads();
        short* dst = ((type == 0) ? qtw : vtw) + (size_t)((b * NH + sg / 3) * DH) * SS + sbase;
        for (int it = 0; it < 4; ++it) {
            int c = it * 256 + t;
            int d = c >> 4, off = (c & 15) * 8;
            *(short8*)(dst + (size_t)d * SS + off) =
                *(const short8*)(&Tt[d * 136 + off]);
        }
    }

    // ---- K pass: LDS transpose -> coalesced [s][d] store
    int kseg = (seg0 % 3 == 1) ? seg0 : (((seg0 + 1) % 3 == 1) ? seg0 + 1 : -1);
    if (kseg >= 0) {
        short* Kt = smem;
        __syncthreads();
        if (seg == kseg) {
            for (int mi = 0; mi < 4; ++mi)
                for (int ni = 0; ni < 4; ++ni)
                    for (int r = 0; r < 4; ++r)
                        Kt[(wr * 64 + mi * 16 + qd * 4 + r) * 72 + ni * 16 + c16] =
                            f2bf(acc[mi][ni][r] + bias4[ni]);
        }
        __syncthreads();
        int bhk = b * NH + kseg / 3;
        int srow = t >> 1, dh = (t & 1) * 32;
        short* gdst = &kw[(size_t)(bhk * SS + sbase + srow) * DH + dh];
        const short* lsrc = &Kt[srow * 72 + dh];
        for (int k = 0; k < 4; ++k)
            *(short8*)(gdst + k * 8) = *(const short8*)(lsrc + k * 8);
    }
}

// ---- flash attention, 32x32x16 MFMA + permlane P-redistribution (R9 best).
// 512-thread blocks (8 waves, 256 q rows) sharing ONE K/V staging pass;
// per-wave inner loop = R6's known-good schedule (KVBLK=64, 2 barriers/kt,
// stride-72 LDS). 47.3us measured, MfmaUtil 28, VALUBusy 37.
__global__ __launch_bounds__(512) void k_attn(const short* __restrict__ qtw,
                                              const short* __restrict__ kw,
                                              const short* __restrict__ vtw,
                                              short* __restrict__ res) {
    __shared__ __align__(16) short Ks[64 * 72];
    __shared__ __align__(16) short Vts[64 * 72];
    int bid = blockIdx.x;
    int q0 = (bid >> 7) * 256;
    int bh = bid & 127;
    int t = threadIdx.x;
    int lane = t & 63, w = t >> 6;  // w in [0,8)
    int l31 = lane & 31, hi = lane >> 5;
    const short* qp = qtw + (size_t)bh * DH * SS;  // [d][s]
    const short* kp = kw + (size_t)bh * SS * DH;   // [s][d]
    const short* vp = vtw + (size_t)bh * DH * SS;  // [d][s]

    // Q B-fragments (32x32x16): n = s = lane&31, elem e -> k = kd*16 + hi*8 + e
    short8 qfrag[4];
    {
        int s = q0 + w * 32 + l31;
        for (int kd = 0; kd < 4; ++kd) {
            short8 q;
            for (int e = 0; e < 8; ++e)
                q[e] = qp[(size_t)(kd * 16 + hi * 8 + e) * SS + s];
            qfrag[kd] = q;
        }
    }

    float l_i = 0.f;
    floatx16 o_acc[2] = {};  // [dt]

    int kr = t >> 3, kc = (t & 7) * 8;  // one short8 per thread covers 64x64 tile
    short8 kreg, vreg;
    kreg = *(const short8*)(&kp[kr * DH + kc]);
    vreg = *(const short8*)(&vp[kr * SS + kc]);

    for (int kt = 0; kt < 16; ++kt) {
        if (kt) __syncthreads();
        *(short8*)(&Ks[kr * 72 + kc]) = kreg;
        *(short8*)(&Vts[kr * 72 + kc]) = vreg;
        __syncthreads();
        if (kt < 15) {
            kreg = *(const short8*)(&kp[((kt + 1) * 64 + kr) * DH + kc]);
            vreg = *(const short8*)(&vp[kr * SS + (kt + 1) * 64 + kc]);
        }

#pragma unroll
        for (int jt = 0; jt < 2; ++jt) {
            // K A-fragments for this 32-row j tile: m = j = jt*32+l31, k = d
            short8 kf[4];
#pragma unroll
            for (int kd = 0; kd < 4; ++kd)
                kf[kd] = *(const short8*)(&Ks[(jt * 32 + l31) * 72 + kd * 16 + hi * 8]);
            // V^T A-fragments for this jt's two 16-wide j halves, both d tiles
            short8 vf0[2], vf1[2];
#pragma unroll
            for (int dt = 0; dt < 2; ++dt) {
                vf0[dt] = *(const short8*)(&Vts[(dt * 32 + l31) * 72 + (jt * 2 + 0) * 16 + hi * 8]);
                vf1[dt] = *(const short8*)(&Vts[(dt * 32 + l31) * 72 + (jt * 2 + 1) * 16 + hi * 8]);
            }

            floatx16 sacc = {};
            __builtin_amdgcn_s_setprio(1);
#pragma unroll
            for (int kd = 0; kd < 4; ++kd)
                sacc = MFMA32(kf[kd], qfrag[kd], sacc);
            __builtin_amdgcn_s_setprio(0);

            // exp2 + pack pairs; u[q] holds rows:
            // u0,u1={0..3}+4hi  u2,u3={8..11}+4hi  u4,u5={16..19}+4hi  u6,u7={24..27}+4hi
            float ls = 0.f;
            unsigned u[8];
#pragma unroll
            for (int r = 0; r < 16; r += 2) {
                float e0 = __builtin_amdgcn_exp2f(sacc[r]);
                float e1 = __builtin_amdgcn_exp2f(sacc[r + 1]);
                ls += e0 + e1;
                u[r >> 1] = pk2_trunc(e0, e1);
            }
            l_i += ls;

            // Redistribute to PV B-fragments (elem e needs row hi*8+e)
            uint2v r02 = __builtin_amdgcn_permlane32_swap(u[0], u[2], false, false);
            uint2v r13 = __builtin_amdgcn_permlane32_swap(u[1], u[3], false, false);
            uint2v r46 = __builtin_amdgcn_permlane32_swap(u[4], u[6], false, false);
            uint2v r57 = __builtin_amdgcn_permlane32_swap(u[5], u[7], false, false);
            union { unsigned w[4]; short8 s; } pf0, pf1;
            pf0.w[0] = r02[0]; pf0.w[1] = r13[0]; pf0.w[2] = r02[1]; pf0.w[3] = r13[1];
            pf1.w[0] = r46[0]; pf1.w[1] = r57[0]; pf1.w[2] = r46[1]; pf1.w[3] = r57[1];

            __builtin_amdgcn_s_setprio(1);
#pragma unroll
            for (int dt = 0; dt < 2; ++dt) {
                o_acc[dt] = MFMA32(vf0[dt], pf0.s, o_acc[dt]);
                o_acc[dt] = MFMA32(vf1[dt], pf1.s, o_acc[dt]);
            }
            __builtin_amdgcn_s_setprio(0);
        }
    }

    int b = bh >> 2, h = bh & 3;
    {
        float l = l_i;
        l += __shfl_xor(l, 32);
        float inv = 1.f / l;
        int s = q0 + w * 32 + l31;
        long base = (long)(b * SS + s) * CC + h * DH;
#pragma unroll
        for (int dt = 0; dt < 2; ++dt) {
#pragma unroll
            for (int q = 0; q < 4; ++q) {
                int d = dt * 32 + q * 8 + hi * 4;
                uint2 ow;
                ow.x = pk2_rn(o_acc[dt][q * 4 + 0] * inv, o_acc[dt][q * 4 + 1] * inv);
                ow.y = pk2_rn(o_acc[dt][q * 4 + 2] * inv, o_acc[dt][q * 4 + 3] * inv);
                *(uint2*)(&res[base + d]) = ow;
            }
        }
    }
}

// ------- out GEMM (transposed): D[c][s] = sum_k res[s][k] W_out[k][c] + b + x -------
// 64(c)x128(s) tiles, grid 1024 = 4 blocks/CU, LDS dbuf 1 barrier/kt (R7 win).
// R11: epilogue via LDS transpose -> float4 fully-coalesced x-load/out-store.
// Old epilogue: 64 scalar VMEM ops/thread, each wave instr scattered over
// 4x64B lines (lane = c16+16*qd spans 4 c-rows). New: acc -> LDS f32 tile
// (stride 68, 2-way bank pattern = free), then each thread owns one c-row
// span: 16 VMEM ops/thread, 1KB/instr coalescing on 67MB of f32 traffic.
__global__ __launch_bounds__(256) void k_out(const short* __restrict__ res,
                                             const short* __restrict__ Wot,
                                             const float* __restrict__ bout,
                                             const float* __restrict__ x,
                                             float* __restrict__ out) {
    __shared__ __align__(16) short smem[15360];  // As[2]|Bs[2] in loop; f32 tile after
    int b = blockIdx.z;
    int m0 = blockIdx.y * 64;   // c
    int n0 = blockIdx.x * 128;  // s
    int t = threadIdx.x;
    int lane = t & 63, wid = t >> 6;
    int wr = wid >> 1, wc = wid & 1;
    int c16 = lane & 15, qd = lane >> 4;

    floatx4 acc[2][4] = {};
    int arow = t >> 2, ac4 = (t & 3) * 8;
    int brow0 = t >> 2, bc0 = (t & 3) * 8;   // j=0 rows 0..63
    int brow1 = brow0 + 64;                  // j=1 rows 64..127
    short8 pa, pb0, pb1;
    pa  = *(const short8*)(&Wot[(m0 + arow) * CC + ac4]);
    pb0 = *(const short8*)(&res[(b * SS + n0 + brow0) * CC + bc0]);
    pb1 = *(const short8*)(&res[(b * SS + n0 + brow1) * CC + bc0]);
    {
        short* As0 = smem;              // 2 x 2560
        short* Bs0 = smem + 5120;       // 2 x 5120
        *(short8*)(&As0[arow * 40 + ac4]) = pa;
        *(short8*)(&Bs0[brow0 * 40 + bc0]) = pb0;
        *(short8*)(&Bs0[brow1 * 40 + bc0]) = pb1;
    }
    __syncthreads();

    int cur = 0;
    for (int kt = 0; kt < 8; ++kt) {
        short* Asc = smem + cur * 2560;
        short* Bsc = smem + 5120 + cur * 5120;
        if (kt < 7) {
            pa  = *(const short8*)(&Wot[(m0 + arow) * CC + (kt + 1) * 32 + ac4]);
            pb0 = *(const short8*)(&res[(b * SS + n0 + brow0) * CC + (kt + 1) * 32 + bc0]);
            pb1 = *(const short8*)(&res[(b * SS + n0 + brow1) * CC + (kt + 1) * 32 + bc0]);
        }
        short8 av[2], bv[4];
        for (int i = 0; i < 2; ++i)
            av[i] = *(const short8*)(&Asc[(wr * 32 + i * 16 + c16) * 40 + qd * 8]);
        for (int i = 0; i < 4; ++i)
            bv[i] = *(const short8*)(&Bsc[(wc * 64 + i * 16 + c16) * 40 + qd * 8]);
        for (int mi = 0; mi < 2; ++mi)
            for (int ni = 0; ni < 4; ++ni)
                acc[mi][ni] = MFMA16(av[mi], bv[ni], acc[mi][ni]);
        if (kt < 7) {
            short* Asn = smem + (cur ^ 1) * 2560;
            short* Bsn = smem + 5120 + (cur ^ 1) * 5120;
            *(short8*)(&Asn[arow * 40 + ac4]) = pa;
            *(short8*)(&Bsn[brow0 * 40 + bc0]) = pb0;
            *(short8*)(&Bsn[brow1 * 40 + bc0]) = pb1;
            __syncthreads();
            cur ^= 1;
        }
    }

    // ---- epilogue: acc -> LDS f32 tile (64c x 64s, stride 68) -> float4 I/O
    float* Tf = (float*)smem;  // 64*68*4 = 17408 B <= 30720 B (As/Bs dead)
    float bias_c = bout[m0 + (t >> 2)];
    for (int p = 0; p < 2; ++p) {
        __syncthreads();
        if (wc == p) {
            for (int mi = 0; mi < 2; ++mi)
                for (int ni = 0; ni < 4; ++ni)
                    for (int r = 0; r < 4; ++r)
                        Tf[(wr * 32 + mi * 16 + qd * 4 + r) * 68 + ni * 16 + c16] =
                            acc[mi][ni][r];
        }
        __syncthreads();
        int c = t >> 2, sq = (t & 3) * 16;
        size_t gbase = ((size_t)(b * CC) + m0 + c) * SS + n0 + p * 64 + sq;
        const float* xrow = x + gbase;
        float* orow = out + gbase;
        const float* trow = &Tf[c * 68 + sq];
        for (int q = 0; q < 4; ++q) {
            float4 xv = *(const float4*)(xrow + q * 4);
            float4 tv = *(const float4*)(trow + q * 4);
            float4 ov;
            ov.x = tv.x + bias_c + xv.x;
            ov.y = tv.y + bias_c + xv.y;
            ov.z = tv.z + bias_c + xv.z;
            ov.w = tv.w + bias_c + xv.w;
            *(float4*)(orow + q * 4) = ov;
        }
    }
}

extern "C" void kernel_launch(void* const* d_in, const int* in_sizes, int n_in,
                              void* d_out, int out_size, void* d_ws, size_t ws_size,
                              hipStream_t stream) {
    const float* x    = (const float*)d_in[0];
    const float* Wqkv = (const float*)d_in[1];
    const float* bqkv = (const float*)d_in[2];
    const float* Wout = (const float*)d_in[3];
    const float* bout = (const float*)d_in[4];
    float* out = (float*)d_out;

    char* ws = (char*)d_ws;
    short* xs_res = (short*)(ws);               // 16,777,216 B  (xs, later reused as res)
    short* qtw    = (short*)(ws + 16777216);    // 16,777,216 B  (Q^T [bh][d][s])
    short* kw     = (short*)(ws + 33554432);    // 16,777,216 B  (K   [bh][s][d])
    short* vtw    = (short*)(ws + 50331648);    // 16,777,216 B  (V^T [bh][d][s])
    short* Wqkv_t = (short*)(ws + 67108864);    //    393,216 B
    short* Wout_t = (short*)(ws + 67502080);    //    131,072 B

    k_prep<<<dim3(3072), 256, 0, stream>>>(x, Wqkv, Wout, xs_res, Wqkv_t, Wout_t);
    k_qkv<<<dim3(1536), 256, 0, stream>>>(xs_res, Wqkv_t, bqkv, qtw, kw, vtw);
    k_attn<<<dim3(512), 512, 0, stream>>>(qtw, kw, vtw, xs_res);
    k_out<<<dim3(8, 4, 32), 256, 0, stream>>>(xs_res, Wout_t, bout, x, out);
}

// Round 12
// 170.043 us; speedup vs baseline: 1.0414x; 1.0414x over previous
//
#include <hip/hip_runtime.h>

#define NH 4
#define DH 64
#define SS 1024
#define CC 256

typedef __attribute__((ext_vector_type(8))) short short8;
typedef __attribute__((ext_vector_type(4))) float floatx4;
typedef __attribute__((ext_vector_type(16))) float floatx16;
typedef __attribute__((ext_vector_type(2))) unsigned uint2v;

#define MFMA16(a, b, c) __builtin_amdgcn_mfma_f32_16x16x32_bf16(a, b, c, 0, 0, 0)
#define MFMA32(a, b, c) __builtin_amdgcn_mfma_f32_32x32x16_bf16(a, b, c, 0, 0, 0)

// q scale 0.125 folded with log2(e) so attention can use exp2 directly
#define QSCALE 0.18033688011112042f

__device__ __forceinline__ short f2bf(float f) {
    union { float f; unsigned u; } v; v.f = f;
    unsigned r = (v.u + 0x7fffu + ((v.u >> 16) & 1u)) >> 16;
    return (short)r;
}
__device__ __forceinline__ unsigned bfrn(float f) {
    union { float f; unsigned u; } v; v.f = f;
    return (v.u + 0x7fffu + ((v.u >> 16) & 1u)) >> 16;
}
__device__ __forceinline__ unsigned pk2_trunc(float a, float b) {
    union { float f; unsigned u; } ua, ub; ua.f = a; ub.f = b;
    return (ua.u >> 16) | (ub.u & 0xFFFF0000u);
}
__device__ __forceinline__ unsigned pk2_rn(float a, float b) {
    return bfrn(a) | (bfrn(b) << 16);
}

// ------- merged prep: x [B][C][S] f32 -> xs [B][S][C] bf16 ; weight transposes -------
__global__ __launch_bounds__(256) void k_prep(const float* __restrict__ x,
                                              const float* __restrict__ Wqkv,
                                              const float* __restrict__ Wout,
                                              short* __restrict__ xs,
                                              short* __restrict__ Wqkv_t,
                                              short* __restrict__ Wout_t) {
    int bid = blockIdx.x;
    if (bid < 2048) {
        __shared__ float tile[64][65];
        int b = bid >> 6;
        int s0 = ((bid >> 2) & 15) * 64;
        int c0 = (bid & 3) * 64;
        int t = threadIdx.x;
        int tx = t & 63, ty = t >> 6;
        for (int i = 0; i < 16; ++i) {
            int c = ty + i * 4;
            tile[tx][c] = x[((b * CC) + (c0 + c)) * SS + s0 + tx];
        }
        __syncthreads();
        for (int i = 0; i < 8; ++i) {
            int s = (t >> 5) + i * 8;
            int cp = (t & 31) * 2;
            short2 v;
            v.x = f2bf(tile[s][cp]);
            v.y = f2bf(tile[s][cp + 1]);
            *(short2*)(&xs[((b * SS) + (s0 + s)) * CC + c0 + cp]) = v;
        }
    } else {
        int idx = (bid - 2048) * 256 + threadIdx.x;
        if (idx < 768 * 256) {
            int n = idx >> 8, k = idx & 255;
            Wqkv_t[idx] = f2bf(Wqkv[k * 768 + n]);
        } else {
            int j = idx - 768 * 256;
            int c = j >> 8, k = j & 255;
            Wout_t[j] = f2bf(Wout[k * 256 + c]);
        }
    }
}

// ---------------- QKV GEMM: [32768,256] @ [256,768] ----------------
// R12: main-loop staging via global_load_lds width=16 (m97 pattern): linear
// unpadded LDS [128][32] per operand; lane l's 16B lands at base + 16*l
// (row = lane>>2, col = (lane&3)*8 -> byte offset 16*lane exactly, satisfying
// the wave-uniform-dest rule). Removes the VGPR round-trip + ds_writes +
// address VALU per kt. Fragment reads accept linear-layout bank conflicts
// (m97: 874 TF with them). Epilogue identical to R9.
__global__ __launch_bounds__(256) void k_qkv(const short* __restrict__ xs,
                                             const short* __restrict__ Wt,
                                             const float* __restrict__ bqkv,
                                             short* __restrict__ qtw,
                                             short* __restrict__ kw,
                                             short* __restrict__ vtw) {
    __shared__ __align__(16) short smem[10240];  // As|Bs linear in loop; transpose tile after
    short* As = smem;           // [128][32] linear
    short* Bs = smem + 4096;    // [128][32] linear
    int bid = blockIdx.x;
    int idx = bid >> 3;
    int m0 = ((bid & 7) * 32 + idx / 6) * 128;
    int n0 = (idx % 6) * 128;
    int t = threadIdx.x;
    int lane = t & 63, wid = t >> 6;
    int wr = wid >> 1, wc = wid & 1;
    int c16 = lane & 15, qd = lane >> 4;

    floatx4 acc[4][4] = {};
    int lrow = lane >> 2, lcol = (lane & 3) * 8;

    for (int kt = 0; kt < 8; ++kt) {
        if (kt) __syncthreads();
#pragma unroll
        for (int j = 0; j < 2; ++j) {
            int r0 = wid * 32 + j * 16;  // this wave's 16-row chunk
            const short* ga = xs + (size_t)(m0 + r0 + lrow) * CC + kt * 32 + lcol;
            const short* gb = Wt + (size_t)(n0 + r0 + lrow) * CC + kt * 32 + lcol;
            __builtin_amdgcn_global_load_lds(
                (const __attribute__((address_space(1))) unsigned*)ga,
                (__attribute__((address_space(3))) unsigned*)(As + r0 * 32), 16, 0, 0);
            __builtin_amdgcn_global_load_lds(
                (const __attribute__((address_space(1))) unsigned*)gb,
                (__attribute__((address_space(3))) unsigned*)(Bs + r0 * 32), 16, 0, 0);
        }
        __syncthreads();  // compiler drains vmcnt before barrier -> LDS valid
        short8 av[4], bv[4];
        for (int i = 0; i < 4; ++i) {
            av[i] = *(const short8*)(&As[(wr * 64 + i * 16 + c16) * 32 + qd * 8]);
            bv[i] = *(const short8*)(&Bs[(wc * 64 + i * 16 + c16) * 32 + qd * 8]);
        }
        for (int mi = 0; mi < 4; ++mi)
            for (int ni = 0; ni < 4; ++ni)
                acc[mi][ni] = MFMA16(av[mi], bv[ni], acc[mi][ni]);
    }

    int b = m0 >> 10, sbase = m0 & 1023;
    int seg = (n0 >> 6) + wc;  // this wave's segment: h*3 + (0=q,1=k,2=v)
    float bias4[4];
    for (int ni = 0; ni < 4; ++ni)
        bias4[ni] = bqkv[n0 + wc * 64 + ni * 16 + c16];

    // ---- Q/V passes: LDS transpose [s][d]->[d][s], then coalesced stores.
    int seg0 = n0 >> 6;
    short* Tt = smem;
    for (int s2 = 0; s2 < 2; ++s2) {
        int sg = seg0 + s2;
        int type = sg % 3;
        if (type == 1) continue;  // k handled below
        float sc = (type == 0) ? QSCALE : 1.f;
        __syncthreads();
        if (wc == s2) {
            for (int mi = 0; mi < 4; ++mi)
                for (int ni = 0; ni < 4; ++ni)
                    for (int r = 0; r < 4; ++r)
                        Tt[(ni * 16 + c16) * 136 + wr * 64 + mi * 16 + qd * 4 + r] =
                            f2bf((acc[mi][ni][r] + bias4[ni]) * sc);
        }
        __syncthreads();
        short* dst = ((type == 0) ? qtw : vtw) + (size_t)((b * NH + sg / 3) * DH) * SS + sbase;
        for (int it = 0; it < 4; ++it) {
            int c = it * 256 + t;
            int d = c >> 4, off = (c & 15) * 8;
            *(short8*)(dst + (size_t)d * SS + off) =
                *(const short8*)(&Tt[d * 136 + off]);
        }
    }

    // ---- K pass: LDS transpose -> coalesced [s][d] store
    int kseg = (seg0 % 3 == 1) ? seg0 : (((seg0 + 1) % 3 == 1) ? seg0 + 1 : -1);
    if (kseg >= 0) {
        short* Kt = smem;
        __syncthreads();
        if (seg == kseg) {
            for (int mi = 0; mi < 4; ++mi)
                for (int ni = 0; ni < 4; ++ni)
                    for (int r = 0; r < 4; ++r)
                        Kt[(wr * 64 + mi * 16 + qd * 4 + r) * 72 + ni * 16 + c16] =
                            f2bf(acc[mi][ni][r] + bias4[ni]);
        }
        __syncthreads();
        int bhk = b * NH + kseg / 3;
        int srow = t >> 1, dh = (t & 1) * 32;
        short* gdst = &kw[(size_t)(bhk * SS + sbase + srow) * DH + dh];
        const short* lsrc = &Kt[srow * 72 + dh];
        for (int k = 0; k < 4; ++k)
            *(short8*)(gdst + k * 8) = *(const short8*)(lsrc + k * 8);
    }
}

// ---- flash attention, 32x32x16 MFMA + permlane P-redistribution (R9 best).
// 512-thread blocks (8 waves, 256 q rows) sharing ONE K/V staging pass;
// per-wave inner loop = R6's known-good schedule (KVBLK=64, 2 barriers/kt,
// stride-72 LDS). 47.3us measured, MfmaUtil 28, VALUBusy 37.
__global__ __launch_bounds__(512) void k_attn(const short* __restrict__ qtw,
                                              const short* __restrict__ kw,
                                              const short* __restrict__ vtw,
                                              short* __restrict__ res) {
    __shared__ __align__(16) short Ks[64 * 72];
    __shared__ __align__(16) short Vts[64 * 72];
    int bid = blockIdx.x;
    int q0 = (bid >> 7) * 256;
    int bh = bid & 127;
    int t = threadIdx.x;
    int lane = t & 63, w = t >> 6;  // w in [0,8)
    int l31 = lane & 31, hi = lane >> 5;
    const short* qp = qtw + (size_t)bh * DH * SS;  // [d][s]
    const short* kp = kw + (size_t)bh * SS * DH;   // [s][d]
    const short* vp = vtw + (size_t)bh * DH * SS;  // [d][s]

    // Q B-fragments (32x32x16): n = s = lane&31, elem e -> k = kd*16 + hi*8 + e
    short8 qfrag[4];
    {
        int s = q0 + w * 32 + l31;
        for (int kd = 0; kd < 4; ++kd) {
            short8 q;
            for (int e = 0; e < 8; ++e)
                q[e] = qp[(size_t)(kd * 16 + hi * 8 + e) * SS + s];
            qfrag[kd] = q;
        }
    }

    float l_i = 0.f;
    floatx16 o_acc[2] = {};  // [dt]

    int kr = t >> 3, kc = (t & 7) * 8;  // one short8 per thread covers 64x64 tile
    short8 kreg, vreg;
    kreg = *(const short8*)(&kp[kr * DH + kc]);
    vreg = *(const short8*)(&vp[kr * SS + kc]);

    for (int kt = 0; kt < 16; ++kt) {
        if (kt) __syncthreads();
        *(short8*)(&Ks[kr * 72 + kc]) = kreg;
        *(short8*)(&Vts[kr * 72 + kc]) = vreg;
        __syncthreads();
        if (kt < 15) {
            kreg = *(const short8*)(&kp[((kt + 1) * 64 + kr) * DH + kc]);
            vreg = *(const short8*)(&vp[kr * SS + (kt + 1) * 64 + kc]);
        }

#pragma unroll
        for (int jt = 0; jt < 2; ++jt) {
            // K A-fragments for this 32-row j tile: m = j = jt*32+l31, k = d
            short8 kf[4];
#pragma unroll
            for (int kd = 0; kd < 4; ++kd)
                kf[kd] = *(const short8*)(&Ks[(jt * 32 + l31) * 72 + kd * 16 + hi * 8]);
            // V^T A-fragments for this jt's two 16-wide j halves, both d tiles
            short8 vf0[2], vf1[2];
#pragma unroll
            for (int dt = 0; dt < 2; ++dt) {
                vf0[dt] = *(const short8*)(&Vts[(dt * 32 + l31) * 72 + (jt * 2 + 0) * 16 + hi * 8]);
                vf1[dt] = *(const short8*)(&Vts[(dt * 32 + l31) * 72 + (jt * 2 + 1) * 16 + hi * 8]);
            }

            floatx16 sacc = {};
            __builtin_amdgcn_s_setprio(1);
#pragma unroll
            for (int kd = 0; kd < 4; ++kd)
                sacc = MFMA32(kf[kd], qfrag[kd], sacc);
            __builtin_amdgcn_s_setprio(0);

            // exp2 + pack pairs; u[q] holds rows:
            // u0,u1={0..3}+4hi  u2,u3={8..11}+4hi  u4,u5={16..19}+4hi  u6,u7={24..27}+4hi
            float ls = 0.f;
            unsigned u[8];
#pragma unroll
            for (int r = 0; r < 16; r += 2) {
                float e0 = __builtin_amdgcn_exp2f(sacc[r]);
                float e1 = __builtin_amdgcn_exp2f(sacc[r + 1]);
                ls += e0 + e1;
                u[r >> 1] = pk2_trunc(e0, e1);
            }
            l_i += ls;

            // Redistribute to PV B-fragments (elem e needs row hi*8+e)
            uint2v r02 = __builtin_amdgcn_permlane32_swap(u[0], u[2], false, false);
            uint2v r13 = __builtin_amdgcn_permlane32_swap(u[1], u[3], false, false);
            uint2v r46 = __builtin_amdgcn_permlane32_swap(u[4], u[6], false, false);
            uint2v r57 = __builtin_amdgcn_permlane32_swap(u[5], u[7], false, false);
            union { unsigned w[4]; short8 s; } pf0, pf1;
            pf0.w[0] = r02[0]; pf0.w[1] = r13[0]; pf0.w[2] = r02[1]; pf0.w[3] = r13[1];
            pf1.w[0] = r46[0]; pf1.w[1] = r57[0]; pf1.w[2] = r46[1]; pf1.w[3] = r57[1];

            __builtin_amdgcn_s_setprio(1);
#pragma unroll
            for (int dt = 0; dt < 2; ++dt) {
                o_acc[dt] = MFMA32(vf0[dt], pf0.s, o_acc[dt]);
                o_acc[dt] = MFMA32(vf1[dt], pf1.s, o_acc[dt]);
            }
            __builtin_amdgcn_s_setprio(0);
        }
    }

    int b = bh >> 2, h = bh & 3;
    {
        float l = l_i;
        l += __shfl_xor(l, 32);
        float inv = 1.f / l;
        int s = q0 + w * 32 + l31;
        long base = (long)(b * SS + s) * CC + h * DH;
#pragma unroll
        for (int dt = 0; dt < 2; ++dt) {
#pragma unroll
            for (int q = 0; q < 4; ++q) {
                int d = dt * 32 + q * 8 + hi * 4;
                uint2 ow;
                ow.x = pk2_rn(o_acc[dt][q * 4 + 0] * inv, o_acc[dt][q * 4 + 1] * inv);
                ow.y = pk2_rn(o_acc[dt][q * 4 + 2] * inv, o_acc[dt][q * 4 + 3] * inv);
                *(uint2*)(&res[base + d]) = ow;
            }
        }
    }
}

// ------- out GEMM (transposed): D[c][s] = sum_k res[s][k] W_out[k][c] + b + x -------
// 64(c)x128(s) tiles, grid 1024 = 4 blocks/CU, LDS dbuf 1 barrier/kt (R7 win).
// R11's LDS-transpose epilogue reverted (measured -5us); original epilogue.
__global__ __launch_bounds__(256) void k_out(const short* __restrict__ res,
                                             const short* __restrict__ Wot,
                                             const float* __restrict__ bout,
                                             const float* __restrict__ x,
                                             float* __restrict__ out) {
    __shared__ short As[2][64 * 40];
    __shared__ short Bs[2][128 * 40];
    int b = blockIdx.z;
    int m0 = blockIdx.y * 64;   // c
    int n0 = blockIdx.x * 128;  // s
    int t = threadIdx.x;
    int lane = t & 63, wid = t >> 6;
    int wr = wid >> 1, wc = wid & 1;
    int c16 = lane & 15, qd = lane >> 4;

    floatx4 acc[2][4] = {};
    int arow = t >> 2, ac4 = (t & 3) * 8;
    int brow0 = t >> 2, bc0 = (t & 3) * 8;   // j=0 rows 0..63
    int brow1 = brow0 + 64;                  // j=1 rows 64..127
    short8 pa, pb0, pb1;
    pa  = *(const short8*)(&Wot[(m0 + arow) * CC + ac4]);
    pb0 = *(const short8*)(&res[(b * SS + n0 + brow0) * CC + bc0]);
    pb1 = *(const short8*)(&res[(b * SS + n0 + brow1) * CC + bc0]);
    *(short8*)(&As[0][arow * 40 + ac4]) = pa;
    *(short8*)(&Bs[0][brow0 * 40 + bc0]) = pb0;
    *(short8*)(&Bs[0][brow1 * 40 + bc0]) = pb1;
    __syncthreads();

    int cur = 0;
    for (int kt = 0; kt < 8; ++kt) {
        if (kt < 7) {
            pa  = *(const short8*)(&Wot[(m0 + arow) * CC + (kt + 1) * 32 + ac4]);
            pb0 = *(const short8*)(&res[(b * SS + n0 + brow0) * CC + (kt + 1) * 32 + bc0]);
            pb1 = *(const short8*)(&res[(b * SS + n0 + brow1) * CC + (kt + 1) * 32 + bc0]);
        }
        short8 av[2], bv[4];
        for (int i = 0; i < 2; ++i)
            av[i] = *(const short8*)(&As[cur][(wr * 32 + i * 16 + c16) * 40 + qd * 8]);
        for (int i = 0; i < 4; ++i)
            bv[i] = *(const short8*)(&Bs[cur][(wc * 64 + i * 16 + c16) * 40 + qd * 8]);
        for (int mi = 0; mi < 2; ++mi)
            for (int ni = 0; ni < 4; ++ni)
                acc[mi][ni] = MFMA16(av[mi], bv[ni], acc[mi][ni]);
        if (kt < 7) {
            *(short8*)(&As[cur ^ 1][arow * 40 + ac4]) = pa;
            *(short8*)(&Bs[cur ^ 1][brow0 * 40 + bc0]) = pb0;
            *(short8*)(&Bs[cur ^ 1][brow1 * 40 + bc0]) = pb1;
            __syncthreads();
            cur ^= 1;
        }
    }

    for (int mi = 0; mi < 2; ++mi) {
        for (int r = 0; r < 4; ++r) {
            int c = m0 + wr * 32 + mi * 16 + qd * 4 + r;
            float bias = bout[c];
            for (int ni = 0; ni < 4; ++ni) {
                int s = n0 + wc * 64 + ni * 16 + c16;
                float v = acc[mi][ni][r] + bias + x[((b * CC) + c) * SS + s];
                out[((b * CC) + c) * SS + s] = v;
            }
        }
    }
}

extern "C" void kernel_launch(void* const* d_in, const int* in_sizes, int n_in,
                              void* d_out, int out_size, void* d_ws, size_t ws_size,
                              hipStream_t stream) {
    const float* x    = (const float*)d_in[0];
    const float* Wqkv = (const float*)d_in[1];
    const float* bqkv = (const float*)d_in[2];
    const float* Wout = (const float*)d_in[3];
    const float* bout = (const float*)d_in[4];
    float* out = (float*)d_out;

    char* ws = (char*)d_ws;
    short* xs_res = (short*)(ws);               // 16,777,216 B  (xs, later reused as res)
    short* qtw    = (short*)(ws + 16777216);    // 16,777,216 B  (Q^T [bh][d][s])
    short* kw     = (short*)(ws + 33554432);    // 16,777,216 B  (K   [bh][s][d])
    short* vtw    = (short*)(ws + 50331648);    // 16,777,216 B  (V^T [bh][d][s])
    short* Wqkv_t = (short*)(ws + 67108864);    //    393,216 B
    short* Wout_t = (short*)(ws + 67502080);    //    131,072 B

    k_prep<<<dim3(3072), 256, 0, stream>>>(x, Wqkv, Wout, xs_res, Wqkv_t, Wout_t);
    k_qkv<<<dim3(1536), 256, 0, stream>>>(xs_res, Wqkv_t, bqkv, qtw, kw, vtw);
    k_attn<<<dim3(512), 512, 0, stream>>>(qtw, kw, vtw, xs_res);
    k_out<<<dim3(8, 4, 32), 256, 0, stream>>>(xs_res, Wout_t, bout, x, out);
}